// Round 16
// baseline (13056.039 us; speedup 1.0000x reference)
//
#include <hip/hip_runtime.h>
#include <stdint.h>

#define B_    512
#define SEQ_  256
#define H_    512
#define NSEQH (SEQ_ * H_)
#define NBLK  256
#define NTHR  (NBLK * 256)

using f32x4 = __attribute__((ext_vector_type(4))) float;
using s16x8 = __attribute__((ext_vector_type(8))) short;

#define WAITVM(N) asm volatile("s_waitcnt vmcnt(" #N ")" ::: "memory")
#define SBAR()    asm volatile("s_barrier" ::: "memory")

__device__ inline unsigned short f2bf(float f) {
  union { float f; uint32_t u; } x; x.f = f;
  uint32_t u = x.u;
  uint32_t r = u + 0x7fffu + ((u >> 16) & 1u);
  return (unsigned short)(r >> 16);
}
__device__ inline float bf2f(unsigned short h) {
  union { float f; uint32_t u; } x; x.u = ((uint32_t)h) << 16;
  return x.f;
}
__device__ inline float h2f(unsigned short u) {
  _Float16 h; __builtin_memcpy(&h, &u, 2); return (float)h;
}
__device__ inline unsigned short f2h(float f) {
  _Float16 h = (_Float16)f; unsigned short u; __builtin_memcpy(&u, &h, 2); return u;
}
__device__ inline float sigf(float x) { return 1.0f / (1.0f + expf(-x)); }

// async global->LDS, cached (read-only data: weights, static inputs)
__device__ inline void gload16(const void* g, void* l) {
  __builtin_amdgcn_global_load_lds(
      (const __attribute__((address_space(1))) void*)g,
      (__attribute__((address_space(3))) void*)l, 16, 0, 0);
}
// async global->LDS, coherent (sc0|sc1): reads the coherent point (MALL) —
// REQUIRED: band producers/consumers span XCDs (R15 lesson).
__device__ inline void gload16c(const void* g, void* l) {
  __builtin_amdgcn_global_load_lds(
      (const __attribute__((address_space(1))) void*)g,
      (__attribute__((address_space(3))) void*)l, 16, 0, 17);
}

__device__ __forceinline__ unsigned short ldh_coh(const unsigned short* p) {
  return __hip_atomic_load(p, __ATOMIC_RELAXED, __HIP_MEMORY_SCOPE_SYSTEM);
}
__device__ __forceinline__ void sth_coh(short* p, unsigned short v) {
  __hip_atomic_store((unsigned short*)p, v, __ATOMIC_RELAXED, __HIP_MEMORY_SCOPE_SYSTEM);
}

// heavy barrier (agent acq_rel). Once, post-prologue.
__device__ __forceinline__ void gbar_heavy(unsigned* bar) {
  __syncthreads();
  if (threadIdx.x == 0) {
    unsigned g = __hip_atomic_load(bar + 1, __ATOMIC_RELAXED, __HIP_MEMORY_SCOPE_AGENT);
    unsigned a = __hip_atomic_fetch_add(bar, 1u, __ATOMIC_ACQ_REL, __HIP_MEMORY_SCOPE_AGENT);
    if (a == (unsigned)(NBLK - 1)) {
      __hip_atomic_store(bar, 0u, __ATOMIC_RELAXED, __HIP_MEMORY_SCOPE_AGENT);
      __hip_atomic_store(bar + 1, g + 1u, __ATOMIC_RELEASE, __HIP_MEMORY_SCOPE_AGENT);
    } else {
      while (__hip_atomic_load(bar + 1, __ATOMIC_ACQUIRE, __HIP_MEMORY_SCOPE_AGENT) == g)
        __builtin_amdgcn_s_sleep(2);
    }
  }
  __syncthreads();
}

// per-band monotonic flags (R14-proven): system scope; signal = drain all
// stores (vmcnt) -> MALL atomic; sc0sc1 data is at MALL before the flag.
__device__ __forceinline__ void flag_signal(unsigned* f) {
  WAITVM(0);
  __syncthreads();
  if (threadIdx.x == 0)
    __hip_atomic_fetch_add(f, 1u, __ATOMIC_RELAXED, __HIP_MEMORY_SCOPE_SYSTEM);
}
__device__ __forceinline__ void flag_wait(unsigned* f, unsigned target) {
  if (threadIdx.x == 0 && target) {
    while (__hip_atomic_load(f, __ATOMIC_RELAXED, __HIP_MEMORY_SCOPE_SYSTEM) < target)
      __builtin_amdgcn_s_sleep(1);
  }
  __syncthreads();
}

__global__ void fill_kernel(float* __restrict__ out, int n, float v) {
  int i = blockIdx.x * blockDim.x + threadIdx.x;
  if (i < n) out[i] = v;
}

// deterministic XCD-aware slot assignment (32 slots/XCD) — R8-proven
__device__ int compute_slot(const int* xcdmap, int myblk) {
  int cnt[8] = {0,0,0,0,0,0,0,0};
  int rank = -1;
  for (int b = 0; b < NBLK; ++b) {
    int x = xcdmap[b] & 7;
    int r = cnt[x]++;
    if (b == myblk) rank = r;
  }
  int myx = xcdmap[myblk] & 7;
  if (rank < 32) return myx * 32 + rank;
  int spill_idx = 0;
  {
    int c2[8] = {0,0,0,0,0,0,0,0};
    for (int b = 0; b < myblk; ++b) {
      int x = xcdmap[b] & 7;
      if (c2[x]++ >= 32) ++spill_idx;
    }
  }
  int k = 0;
  for (int g = 0; g < 8; ++g) {
    int filled = cnt[g] < 32 ? cnt[g] : 32;
    for (int rr = filled; rr < 32; ++rr) {
      if (k == spill_idx) return g * 32 + rr;
      ++k;
    }
  }
  return 0;
}

// ---------------------------------------------------------------------------
// G1 (R14-identical): h_upd = h + Tm1*tanh(h @ Wd.T + bd). 32x32 tile.
// Paired-reuse set (16 KB): A_hi A_lo W_hi W_lo; 6 MFMA/kk; 8 iters,
// 4 LDS sets, single barrier/iter, 3-deep; waits 8/4/0.
// ---------------------------------------------------------------------------
template<bool CVT>
__device__ __forceinline__ void g1_phase(
    char* LDS, int m0, int n0,
    const short* hhi, const short* hlo,
    const short* Wds, const float* bd, const float* tm1,
    short* huhi, short* hulo,
    const unsigned short* lo0_t, short* xhhi, short* xhlo)
{
  const int tid = threadIdx.x;
  const int w = tid >> 6, l = tid & 63;
  const int sr = tid >> 3;               // tile row 0..31
  const int scs = (tid & 7) ^ (sr & 7);  // pre-swizzled source chunk

  auto stage = [&](int kt) {
    char* base = LDS + (kt & 3) * 16384;
    const int kb = kt << 6;
    const size_t aoff = (size_t)(m0 + sr) * H_ + kb + scs * 8;
    gload16c(hhi + aoff, base + w * 1024);
    gload16c(hlo + aoff, base + 4096 + w * 1024);
    const size_t boff = (size_t)(n0 + sr) * 1024 + kb + scs * 8;
    gload16(Wds + boff,       base + 8192  + w * 1024);
    gload16(Wds + boff + 512, base + 12288 + w * 1024);
  };

  stage(0); stage(1); stage(2);

  const int wm = w & 1, wn = w >> 1;
  const int ar = wm * 16 + (l & 15);
  const int br = wn * 16 + (l & 15);
  const int koff = (l >> 4) * 16;
  const int aswz = (ar & 7) << 4;
  const int bswz = (br & 7) << 4;

  f32x4 acc = {0.f, 0.f, 0.f, 0.f};

  for (int kt = 0; kt < 8; ++kt) {
    if (kt < 6)       WAITVM(8);
    else if (kt == 6) WAITVM(4);
    else              WAITVM(0);
    SBAR();
    if (kt + 3 < 8) stage(kt + 3);
    char* base = LDS + (kt & 3) * 16384;
#pragma unroll
    for (int k2 = 0; k2 < 2; ++k2) {
      const int ao = (ar * 128 + k2 * 64 + koff) ^ aswz;
      const int bo = (br * 128 + k2 * 64 + koff) ^ bswz;
      s16x8 a_hi = *(const s16x8*)(base + ao);
      s16x8 a_lo = *(const s16x8*)(base + 4096 + ao);
      s16x8 b_hi = *(const s16x8*)(base + 8192 + bo);
      s16x8 b_lo = *(const s16x8*)(base + 12288 + bo);
      acc = __builtin_amdgcn_mfma_f32_16x16x32_bf16(a_hi, b_hi, acc, 0, 0, 0);
      acc = __builtin_amdgcn_mfma_f32_16x16x32_bf16(a_lo, b_hi, acc, 0, 0, 0);
      acc = __builtin_amdgcn_mfma_f32_16x16x32_bf16(a_hi, b_lo, acc, 0, 0, 0);
    }
  }

  const int n_abs = n0 + wn * 16 + (l & 15);
  const int mbase = m0 + wm * 16 + (l >> 4) * 4;
  const float bv = bd[n_abs];
#pragma unroll
  for (int r = 0; r < 4; ++r) {
    const int m_abs = mbase + r;
    const size_t off = (size_t)m_abs * H_ + n_abs;
    float cst = tanhf(acc[r] + bv);
    float hv = bf2f(ldh_coh((const unsigned short*)hhi + off)) +
               bf2f(ldh_coh((const unsigned short*)hlo + off));
    float hu = hv + tm1[m_abs] * cst;
    unsigned short hi = f2bf(hu);
    sth_coh(huhi + off, hi);
    sth_coh(hulo + off, f2bf(hu - bf2f(hi)));
    if (CVT) {
      float xv = h2f(ldh_coh(lo0_t + (size_t)m_abs * NSEQH + n_abs));
      unsigned short xh = f2bf(xv);
      sth_coh(xhhi + off, xh);
      sth_coh(xhlo + off, f2bf(xv - bf2f(xh)));
    }
  }
}

// ---------------------------------------------------------------------------
// G2: z = [x,h_upd] @ W.T + b -> cell update. 64m x (16j x 4g).
// CHANGE vs R14: 4 LDS sets x 32 KB (shares base 0 with G1 — phases are
// sequential), single barrier/iter, 3-deep prefetch, waits 16/8/0.
// ---------------------------------------------------------------------------
template<int K, int XK, int XSTR, bool STORE_LO0, bool XCOH>
__device__ __forceinline__ void g2_phase(
    char* LDS, int m0, int j0,
    const short* xhi, const short* xlo,
    const short* huhi, const short* hulo,
    const short* Wsp, const float* bias,
    f32x4& cv, short* hhi, short* hlo,
    unsigned short* lo0_t)
{
  constexpr int NT = K / 64;
  constexpr int KPS = 2 * K;
  const int tid = threadIdx.x;
  const int w = tid >> 6, l = tid & 63;

  auto stage = [&](int kt) {
    char* base = LDS + (kt & 3) * 32768;
    const int kb = kt << 6;
#pragma unroll
    for (int j = 0; j < 2; ++j) {
      const int s = tid + j * 256;
      const int r = s >> 3;
      const int cs = (s & 7) ^ (r & 7);
      char* dhi = base + j * 4096 + w * 1024;
      char* dlo = base + 8192 + j * 4096 + w * 1024;
      if (kb < XK) {
        const size_t aoff = (size_t)(m0 + r) * XSTR + kb + cs * 8;
        if (XCOH) { gload16c(xhi + aoff, dhi); gload16c(xlo + aoff, dlo); }
        else      { gload16 (xhi + aoff, dhi); gload16 (xlo + aoff, dlo); }
      } else {
        const size_t aoff = (size_t)(m0 + r) * H_ + (kb - XK) + cs * 8;
        gload16c(huhi + aoff, dhi);
        gload16c(hulo + aoff, dlo);
      }
      const int src_n = (r >> 4) * H_ + j0 + (r & 15);
      const size_t boff = (size_t)src_n * KPS + kb + cs * 8;
      gload16(Wsp + boff,     base + 16384 + j * 4096 + w * 1024);
      gload16(Wsp + boff + K, base + 24576 + j * 4096 + w * 1024);
    }
  };

  stage(0); stage(1); stage(2);

  const int ar = w * 16 + (l & 15);
  const int swz_a = (ar & 7) << 4;
  const int koff = (l >> 4) * 16;

  f32x4 acc[4];
#pragma unroll
  for (int i = 0; i < 4; ++i) acc[i] = (f32x4){0.f, 0.f, 0.f, 0.f};

  for (int kt = 0; kt < NT; ++kt) {
    if (kt < NT - 2)       WAITVM(16);
    else if (kt == NT - 2) WAITVM(8);
    else                   WAITVM(0);
    SBAR();
    if (kt + 3 < NT) stage(kt + 3);
    char* base = LDS + (kt & 3) * 32768;
#pragma unroll
    for (int k2 = 0; k2 < 2; ++k2) {
      const int ao = (ar * 128 + k2 * 64 + koff) ^ swz_a;
      s16x8 a_hi = *(const s16x8*)(base + ao);
      s16x8 a_lo = *(const s16x8*)(base + 8192 + ao);
#pragma unroll
      for (int nf = 0; nf < 4; ++nf) {
        const int br = nf * 16 + (l & 15);
        const int bo = (br * 128 + k2 * 64 + koff) ^ ((br & 7) << 4);
        s16x8 b_hi = *(const s16x8*)(base + 16384 + bo);
        s16x8 b_lo = *(const s16x8*)(base + 24576 + bo);
        acc[nf] = __builtin_amdgcn_mfma_f32_16x16x32_bf16(a_hi, b_hi, acc[nf], 0, 0, 0);
        acc[nf] = __builtin_amdgcn_mfma_f32_16x16x32_bf16(a_lo, b_hi, acc[nf], 0, 0, 0);
        acc[nf] = __builtin_amdgcn_mfma_f32_16x16x32_bf16(a_hi, b_lo, acc[nf], 0, 0, 0);
      }
    }
  }

  const int j_abs = j0 + (l & 15);
  const float bi  = bias[j_abs];
  const float bfv = bias[H_ + j_abs];
  const float bo  = bias[2 * H_ + j_abs];
  const float bg  = bias[3 * H_ + j_abs];
  const int mbase = m0 + w * 16 + (l >> 4) * 4;
#pragma unroll
  for (int r = 0; r < 4; ++r) {
    const int m_abs = mbase + r;
    float zi = acc[0][r] + bi;
    float zf = acc[1][r] + bfv;
    float zo = acc[2][r] + bo;
    float zg = acc[3][r] + bg;
    float cn = sigf(zf) * cv[r] + sigf(zi) * tanhf(zg);
    float hn = sigf(zo) * tanhf(cn);
    cv[r] = cn;
    const size_t off = (size_t)m_abs * H_ + j_abs;
    unsigned short hi = f2bf(hn);
    sth_coh(hhi + off, hi);
    sth_coh(hlo + off, f2bf(hn - bf2f(hi)));
    if (STORE_LO0)
      sth_coh((short*)(lo0_t + (size_t)m_abs * NSEQH + j_abs), f2h(hn));
  }
}

// ---------------------------------------------------------------------------
// Persistent kernel: R14 structure (per-band flags, system-coherent data).
// ---------------------------------------------------------------------------
__global__ __launch_bounds__(256, 1) void persist(
    const float* inputs,
    const float* W0, const float* b0, const float* Wd0, const float* bd0,
    const float* W1, const float* b1, const float* Wd1, const float* bd1,
    float* out,
    unsigned short* lo0, short* xinhi, short* xinlo,
    short* hhi, short* hlo, short* huhi, short* hulo,
    short* xhhi, short* xhlo,
    float* Tm1T, short* Wd0s, short* Wd1s, short* W0s, short* W1s,
    unsigned* bar, int* xcdmap)
{
  __shared__ __align__(16) char LDS[131072];
  const int gtid = blockIdx.x * 256 + threadIdx.x;

  if (threadIdx.x == 0) {
    unsigned xcc;
    asm volatile("s_getreg_b32 %0, hwreg(20, 0, 32)" : "=s"(xcc)); // HW_REG_XCC_ID
    xcdmap[blockIdx.x] = (int)(xcc & 7u);
  }

  auto dosplit = [&](const float* W, short* Ws, int N, int Ksrc, int Kpad, int pad_at) {
    const int total = N * Kpad;
    for (int idx = gtid; idx < total; idx += NTHR) {
      int n = idx / Kpad, c = idx - n * Kpad;
      int sc = c;
      if (pad_at >= 0) { if (c == pad_at) sc = -1; else if (c > pad_at) sc = c - 1; }
      float v = 0.f;
      if (sc >= 0 && sc < Ksrc) v = W[(size_t)n * Ksrc + sc];
      unsigned short hi = f2bf(v);
      unsigned short lo = f2bf(v - bf2f(hi));
      size_t base = (size_t)n * (2 * Kpad);
      Ws[base + c]        = (short)hi;
      Ws[base + Kpad + c] = (short)lo;
    }
  };
  dosplit(Wd0, Wd0s, 512, 512, 512, -1);
  dosplit(Wd1, Wd1s, 512, 512, 512, -1);
  dosplit(W0, W0s, 2048, 575, 576, 63);
  dosplit(W1, W1s, 2048, 1024, 1024, -1);
  for (int idx = gtid; idx < B_ * SEQ_ * 64; idx += NTHR) {
    float v = inputs[idx];
    unsigned short hi = f2bf(v);
    xinhi[idx] = (short)hi;
    xinlo[idx] = (short)f2bf(v - bf2f(hi));
  }
  for (int idx = gtid; idx < B_ * SEQ_; idx += NTHR) {
    int b = idx / SEQ_, t = idx - b * SEQ_;
    float dt = inputs[(size_t)b * (SEQ_ * 64) + t * 64 + 63];
    Tm1T[t * B_ + b] = 1.0f / logf(dt + 2.7183f) - 1.0f;
  }
  for (int idx = gtid; idx < B_ * H_; idx += NTHR) {
    hhi[idx] = 0; hlo[idx] = 0;
  }
  gbar_heavy(bar);

  const int myw = compute_slot(xcdmap, blockIdx.x);
  const int wg = myw >> 5, rr = myw & 31;
  const int g1_n0 = (wg * 2 + (rr & 1)) * 32;   // 16 n-slices, 2 per XCD
  const int g1_m0 = (rr >> 1) * 32;             // 16 m-tiles per n
  const int g2_j0 = (wg * 4 + (rr & 3)) * 16;   // 32 j-slices, 4 per XCD
  const int g2_m0 = (rr >> 2) * 64;             // 8 m-tiles per j

  const int t = rr >> 2;                 // band 0..7 (rows 64t..64t+63)
  const int cid = wg * 4 + (rr & 3);     // 0..31 within band
  unsigned* g1d = bar + 512 + t * 32;    // per-band monotonic counters
  unsigned* g2d = bar + 768 + t * 32;
  unsigned* zd  = bar + 256 + t * 32;

  for (int layer = 0; layer < 2; ++layer) {
    f32x4 cv = {0.f, 0.f, 0.f, 0.f};
    if (layer == 1) {
      flag_wait(g2d, 32u * SEQ_);
      const size_t base = (size_t)t * 64 * H_;
      for (int i = cid * 256 + threadIdx.x; i < 64 * H_; i += 32 * 256) {
        sth_coh(hhi + base + i, 0); sth_coh(hlo + base + i, 0);
      }
      flag_signal(zd);
      flag_wait(zd, 32u);
    }
    for (int s = 0; s < SEQ_; ++s) {
      const unsigned ss = (unsigned)(layer * SEQ_ + s);
      const int torig = SEQ_ - 1 - s;
      flag_wait(g2d, 32u * ss);            // band h(s-1) ready; hu WAR clear
      if (layer == 0)
        g1_phase<false>(LDS, g1_m0, g1_n0, hhi, hlo, Wd0s, bd0,
                        Tm1T + (size_t)torig * B_, huhi, hulo,
                        nullptr, nullptr, nullptr);
      else
        g1_phase<true>(LDS, g1_m0, g1_n0, hhi, hlo, Wd1s, bd1,
                       Tm1T + (size_t)torig * B_, huhi, hulo,
                       lo0 + (size_t)torig * H_, xhhi, xhlo);
      flag_signal(g1d);
      flag_wait(g1d, 32u * (ss + 1));      // band hu/xh ready
      if (layer == 0)
        g2_phase<576, 64, SEQ_ * 64, true, false>(
            LDS, g2_m0, g2_j0,
            xinhi + (size_t)torig * 64, xinlo + (size_t)torig * 64,
            huhi, hulo, W0s, b0, cv, hhi, hlo,
            lo0 + (size_t)s * H_);
      else
        g2_phase<1024, 512, H_, false, true>(
            LDS, g2_m0, g2_j0,
            xhhi, xhlo, huhi, hulo, W1s, b1,
            cv, hhi, hlo, nullptr);
      flag_signal(g2d);
    }
  }

  // band-local output writeback (wait for whole band's last G2)
  flag_wait(g2d, 32u * (unsigned)(2 * SEQ_));
  {
    const size_t base = (size_t)t * 64 * H_;
    for (int i = cid * 256 + threadIdx.x; i < 64 * H_; i += 32 * 256)
      out[base + i] = bf2f(ldh_coh((const unsigned short*)hhi + base + i)) +
                      bf2f(ldh_coh((const unsigned short*)hlo + base + i));
  }
}

extern "C" void kernel_launch(void* const* d_in, const int* in_sizes, int n_in,
                              void* d_out, int out_size, void* d_ws, size_t ws_size,
                              hipStream_t stream) {
  const float* inputs = (const float*)d_in[0];
  const float* W0  = (const float*)d_in[1];
  const float* b0  = (const float*)d_in[2];
  const float* Wd0 = (const float*)d_in[3];
  const float* bd0 = (const float*)d_in[4];
  const float* W1  = (const float*)d_in[5];
  const float* b1  = (const float*)d_in[6];
  const float* Wd1 = (const float*)d_in[7];
  const float* bd1 = (const float*)d_in[8];

  char* ws = (char*)d_ws;
  size_t off = 0;
  auto alloc = [&](size_t bytes) -> char* {
    char* p = ws + off;
    off += (bytes + 1023) & ~(size_t)1023;
    return p;
  };
  unsigned* bar = (unsigned*)alloc(4096);
  int* xcdmap = (int*)alloc(NBLK * 4);
  unsigned short* lo0 = (unsigned short*)alloc((size_t)B_ * SEQ_ * H_ * 2); // fp16
  short* xinhi = (short*)alloc((size_t)B_ * SEQ_ * 64 * 2);
  short* xinlo = (short*)alloc((size_t)B_ * SEQ_ * 64 * 2);
  short* hhi   = (short*)alloc((size_t)B_ * H_ * 2);
  short* hlo   = (short*)alloc((size_t)B_ * H_ * 2);
  short* huhi  = (short*)alloc((size_t)B_ * H_ * 2);
  short* hulo  = (short*)alloc((size_t)B_ * H_ * 2);
  short* xhhi  = (short*)alloc((size_t)B_ * H_ * 2);
  short* xhlo  = (short*)alloc((size_t)B_ * H_ * 2);
  float* Tm1T  = (float*)alloc((size_t)SEQ_ * B_ * 4);
  short* Wd0s  = (short*)alloc((size_t)512 * 1024 * 2);
  short* Wd1s  = (short*)alloc((size_t)512 * 1024 * 2);
  short* W0s   = (short*)alloc((size_t)2048 * 1152 * 2);
  short* W1s   = (short*)alloc((size_t)2048 * 2048 * 2);

  if (off > ws_size) {
    fill_kernel<<<(out_size + 255) / 256, 256, 0, stream>>>(
        (float*)d_out, out_size, (float)(ws_size >> 20));
    return;
  }

  hipMemsetAsync(bar, 0, 4096, stream);
  persist<<<NBLK, 256, 0, stream>>>(
      inputs, W0, b0, Wd0, bd0, W1, b1, Wd1, bd1,
      (float*)d_out,
      lo0, xinhi, xinlo,
      hhi, hlo, huhi, hulo, xhhi, xhlo,
      Tm1T, Wd0s, Wd1s, W0s, W1s, bar, xcdmap);
}

// Round 17
// 9226.479 us; speedup vs baseline: 1.4151x; 1.4151x over previous
//
#include <hip/hip_runtime.h>
#include <stdint.h>

#define B_    512
#define SEQ_  256
#define H_    512
#define NSEQH (SEQ_ * H_)
#define NBLK  256
#define NTHR  (NBLK * 256)

using f32x4 = __attribute__((ext_vector_type(4))) float;
using s16x8 = __attribute__((ext_vector_type(8))) short;

#define WAITVM(N) asm volatile("s_waitcnt vmcnt(" #N ")" ::: "memory")
#define SBAR()    asm volatile("s_barrier" ::: "memory")

__device__ inline unsigned short f2bf(float f) {
  union { float f; uint32_t u; } x; x.f = f;
  uint32_t u = x.u;
  uint32_t r = u + 0x7fffu + ((u >> 16) & 1u);
  return (unsigned short)(r >> 16);
}
__device__ inline float bf2f(unsigned short h) {
  union { float f; uint32_t u; } x; x.u = ((uint32_t)h) << 16;
  return x.f;
}
__device__ inline float h2f(unsigned short u) {
  _Float16 h; __builtin_memcpy(&h, &u, 2); return (float)h;
}
__device__ inline unsigned short f2h(float f) {
  _Float16 h = (_Float16)f; unsigned short u; __builtin_memcpy(&u, &h, 2); return u;
}
__device__ inline float sigf(float x) { return 1.0f / (1.0f + expf(-x)); }

// async global->LDS, cached (read-only data: weights, static inputs)
__device__ inline void gload16(const void* g, void* l) {
  __builtin_amdgcn_global_load_lds(
      (const __attribute__((address_space(1))) void*)g,
      (__attribute__((address_space(3))) void*)l, 16, 0, 0);
}
// async global->LDS, coherent (sc0|sc1): reads the coherent point (MALL) —
// required: band producers/consumers span XCDs (R15 lesson).
__device__ inline void gload16c(const void* g, void* l) {
  __builtin_amdgcn_global_load_lds(
      (const __attribute__((address_space(1))) void*)g,
      (__attribute__((address_space(3))) void*)l, 16, 0, 17);
}

__device__ __forceinline__ unsigned short ldh_coh(const unsigned short* p) {
  return __hip_atomic_load(p, __ATOMIC_RELAXED, __HIP_MEMORY_SCOPE_SYSTEM);
}
__device__ __forceinline__ void sth_coh(short* p, unsigned short v) {
  __hip_atomic_store((unsigned short*)p, v, __ATOMIC_RELAXED, __HIP_MEMORY_SCOPE_SYSTEM);
}

// heavy barrier (agent acq_rel). Once, post-prologue.
__device__ __forceinline__ void gbar_heavy(unsigned* bar) {
  __syncthreads();
  if (threadIdx.x == 0) {
    unsigned g = __hip_atomic_load(bar + 1, __ATOMIC_RELAXED, __HIP_MEMORY_SCOPE_AGENT);
    unsigned a = __hip_atomic_fetch_add(bar, 1u, __ATOMIC_ACQ_REL, __HIP_MEMORY_SCOPE_AGENT);
    if (a == (unsigned)(NBLK - 1)) {
      __hip_atomic_store(bar, 0u, __ATOMIC_RELAXED, __HIP_MEMORY_SCOPE_AGENT);
      __hip_atomic_store(bar + 1, g + 1u, __ATOMIC_RELEASE, __HIP_MEMORY_SCOPE_AGENT);
    } else {
      while (__hip_atomic_load(bar + 1, __ATOMIC_ACQUIRE, __HIP_MEMORY_SCOPE_AGENT) == g)
        __builtin_amdgcn_s_sleep(2);
    }
  }
  __syncthreads();
}

// per-band monotonic flags (R14-proven): system scope; signal = drain all
// stores (vmcnt) -> MALL atomic; sc0sc1 data is at MALL before the flag.
__device__ __forceinline__ void flag_signal(unsigned* f) {
  WAITVM(0);
  __syncthreads();
  if (threadIdx.x == 0)
    __hip_atomic_fetch_add(f, 1u, __ATOMIC_RELAXED, __HIP_MEMORY_SCOPE_SYSTEM);
}
__device__ __forceinline__ void flag_wait(unsigned* f, unsigned target) {
  if (threadIdx.x == 0 && target) {
    while (__hip_atomic_load(f, __ATOMIC_RELAXED, __HIP_MEMORY_SCOPE_SYSTEM) < target)
      __builtin_amdgcn_s_sleep(1);
  }
  __syncthreads();
}

__global__ void fill_kernel(float* __restrict__ out, int n, float v) {
  int i = blockIdx.x * blockDim.x + threadIdx.x;
  if (i < n) out[i] = v;
}

// deterministic XCD-aware slot assignment (32 slots/XCD) — R8-proven
__device__ int compute_slot(const int* xcdmap, int myblk) {
  int cnt[8] = {0,0,0,0,0,0,0,0};
  int rank = -1;
  for (int b = 0; b < NBLK; ++b) {
    int x = xcdmap[b] & 7;
    int r = cnt[x]++;
    if (b == myblk) rank = r;
  }
  int myx = xcdmap[myblk] & 7;
  if (rank < 32) return myx * 32 + rank;
  int spill_idx = 0;
  {
    int c2[8] = {0,0,0,0,0,0,0,0};
    for (int b = 0; b < myblk; ++b) {
      int x = xcdmap[b] & 7;
      if (c2[x]++ >= 32) ++spill_idx;
    }
  }
  int k = 0;
  for (int g = 0; g < 8; ++g) {
    int filled = cnt[g] < 32 ? cnt[g] : 32;
    for (int rr = filled; rr < 32; ++rr) {
      if (k == spill_idx) return g * 32 + rr;
      ++k;
    }
  }
  return 0;
}

// ---------------------------------------------------------------------------
// G1: h_upd = h + Tm1*tanh(h @ Wd.T + bd). 32x32 tile.
// Paired-reuse set (16 KB): A_hi A_lo W_hi W_lo; 6 MFMA/kk; 8 iters,
// 4 LDS sets, single barrier/iter, 3-deep; waits 8/4/0.
// ---------------------------------------------------------------------------
template<bool CVT>
__device__ __forceinline__ void g1_phase(
    char* LDS, int m0, int n0,
    const short* hhi, const short* hlo,
    const short* Wds, const float* bd, const float* tm1,
    short* huhi, short* hulo,
    const unsigned short* lo0_t, short* xhhi, short* xhlo)
{
  const int tid = threadIdx.x;
  const int w = tid >> 6, l = tid & 63;
  const int sr = tid >> 3;               // tile row 0..31
  const int scs = (tid & 7) ^ (sr & 7);  // pre-swizzled source chunk

  auto stage = [&](int kt) {
    char* base = LDS + (kt & 3) * 16384;
    const int kb = kt << 6;
    const size_t aoff = (size_t)(m0 + sr) * H_ + kb + scs * 8;
    gload16c(hhi + aoff, base + w * 1024);
    gload16c(hlo + aoff, base + 4096 + w * 1024);
    const size_t boff = (size_t)(n0 + sr) * 1024 + kb + scs * 8;
    gload16(Wds + boff,       base + 8192  + w * 1024);
    gload16(Wds + boff + 512, base + 12288 + w * 1024);
  };

  stage(0); stage(1); stage(2);

  const int wm = w & 1, wn = w >> 1;
  const int ar = wm * 16 + (l & 15);
  const int br = wn * 16 + (l & 15);
  const int koff = (l >> 4) * 16;
  const int aswz = (ar & 7) << 4;
  const int bswz = (br & 7) << 4;

  f32x4 acc = {0.f, 0.f, 0.f, 0.f};

  for (int kt = 0; kt < 8; ++kt) {
    if (kt < 6)       WAITVM(8);
    else if (kt == 6) WAITVM(4);
    else              WAITVM(0);
    SBAR();
    if (kt + 3 < 8) stage(kt + 3);
    char* base = LDS + (kt & 3) * 16384;
#pragma unroll
    for (int k2 = 0; k2 < 2; ++k2) {
      const int ao = (ar * 128 + k2 * 64 + koff) ^ aswz;
      const int bo = (br * 128 + k2 * 64 + koff) ^ bswz;
      s16x8 a_hi = *(const s16x8*)(base + ao);
      s16x8 a_lo = *(const s16x8*)(base + 4096 + ao);
      s16x8 b_hi = *(const s16x8*)(base + 8192 + bo);
      s16x8 b_lo = *(const s16x8*)(base + 12288 + bo);
      acc = __builtin_amdgcn_mfma_f32_16x16x32_bf16(a_hi, b_hi, acc, 0, 0, 0);
      acc = __builtin_amdgcn_mfma_f32_16x16x32_bf16(a_lo, b_hi, acc, 0, 0, 0);
      acc = __builtin_amdgcn_mfma_f32_16x16x32_bf16(a_hi, b_lo, acc, 0, 0, 0);
    }
  }

  const int n_abs = n0 + wn * 16 + (l & 15);
  const int mbase = m0 + wm * 16 + (l >> 4) * 4;
  const float bv = bd[n_abs];
#pragma unroll
  for (int r = 0; r < 4; ++r) {
    const int m_abs = mbase + r;
    const size_t off = (size_t)m_abs * H_ + n_abs;
    float cst = tanhf(acc[r] + bv);
    float hv = bf2f(ldh_coh((const unsigned short*)hhi + off)) +
               bf2f(ldh_coh((const unsigned short*)hlo + off));
    float hu = hv + tm1[m_abs] * cst;
    unsigned short hi = f2bf(hu);
    sth_coh(huhi + off, hi);
    sth_coh(hulo + off, f2bf(hu - bf2f(hi)));
    if (CVT) {
      float xv = h2f(ldh_coh(lo0_t + (size_t)m_abs * NSEQH + n_abs));
      unsigned short xh = f2bf(xv);
      sth_coh(xhhi + off, xh);
      sth_coh(xhlo + off, f2bf(xv - bf2f(xh)));
    }
  }
}

// ---------------------------------------------------------------------------
// G2: z = [x,h_upd] @ W.T + b -> cell update. 64m x (16j x 4g).
// Paired-reuse set (32 KB): A_hi A_lo W_hi W_lo; 24 MFMA/kk. NT iters,
// 2 LDS sets, two barriers/iter; waits 8/0. c-state in registers.
// (R16 lesson: keep the tight 2-set loop — deeper prefetch destroys
// inter-block L2 temporal reuse of weights and doubles FETCH.)
// ---------------------------------------------------------------------------
template<int K, int XK, int XSTR, bool STORE_LO0, bool XCOH>
__device__ __forceinline__ void g2_phase(
    char* LDS, int m0, int j0,
    const short* xhi, const short* xlo,
    const short* huhi, const short* hulo,
    const short* Wsp, const float* bias,
    f32x4& cv, short* hhi, short* hlo,
    unsigned short* lo0_t)
{
  constexpr int NT = K / 64;
  constexpr int KPS = 2 * K;
  const int tid = threadIdx.x;
  const int w = tid >> 6, l = tid & 63;

  auto stage = [&](int kt) {
    char* base = LDS + 65536 + (kt & 1) * 32768;
    const int kb = kt << 6;
#pragma unroll
    for (int j = 0; j < 2; ++j) {
      const int s = tid + j * 256;
      const int r = s >> 3;
      const int cs = (s & 7) ^ (r & 7);
      char* dhi = base + j * 4096 + w * 1024;
      char* dlo = base + 8192 + j * 4096 + w * 1024;
      if (kb < XK) {
        const size_t aoff = (size_t)(m0 + r) * XSTR + kb + cs * 8;
        if (XCOH) { gload16c(xhi + aoff, dhi); gload16c(xlo + aoff, dlo); }
        else      { gload16 (xhi + aoff, dhi); gload16 (xlo + aoff, dlo); }
      } else {
        const size_t aoff = (size_t)(m0 + r) * H_ + (kb - XK) + cs * 8;
        gload16c(huhi + aoff, dhi);
        gload16c(hulo + aoff, dlo);
      }
      const int src_n = (r >> 4) * H_ + j0 + (r & 15);
      const size_t boff = (size_t)src_n * KPS + kb + cs * 8;
      gload16(Wsp + boff,     base + 16384 + j * 4096 + w * 1024);
      gload16(Wsp + boff + K, base + 24576 + j * 4096 + w * 1024);
    }
  };

  stage(0); stage(1);

  const int ar = w * 16 + (l & 15);
  const int swz_a = (ar & 7) << 4;
  const int koff = (l >> 4) * 16;

  f32x4 acc[4];
#pragma unroll
  for (int i = 0; i < 4; ++i) acc[i] = (f32x4){0.f, 0.f, 0.f, 0.f};

  for (int kt = 0; kt < NT; ++kt) {
    if (kt + 1 < NT) WAITVM(8);
    else             WAITVM(0);
    SBAR();
    char* base = LDS + 65536 + (kt & 1) * 32768;
#pragma unroll
    for (int k2 = 0; k2 < 2; ++k2) {
      const int ao = (ar * 128 + k2 * 64 + koff) ^ swz_a;
      s16x8 a_hi = *(const s16x8*)(base + ao);
      s16x8 a_lo = *(const s16x8*)(base + 8192 + ao);
#pragma unroll
      for (int nf = 0; nf < 4; ++nf) {
        const int br = nf * 16 + (l & 15);
        const int bo = (br * 128 + k2 * 64 + koff) ^ ((br & 7) << 4);
        s16x8 b_hi = *(const s16x8*)(base + 16384 + bo);
        s16x8 b_lo = *(const s16x8*)(base + 24576 + bo);
        acc[nf] = __builtin_amdgcn_mfma_f32_16x16x32_bf16(a_hi, b_hi, acc[nf], 0, 0, 0);
        acc[nf] = __builtin_amdgcn_mfma_f32_16x16x32_bf16(a_lo, b_hi, acc[nf], 0, 0, 0);
        acc[nf] = __builtin_amdgcn_mfma_f32_16x16x32_bf16(a_hi, b_lo, acc[nf], 0, 0, 0);
      }
    }
    SBAR();
    if (kt + 2 < NT) stage(kt + 2);
  }

  const int j_abs = j0 + (l & 15);
  const float bi  = bias[j_abs];
  const float bfv = bias[H_ + j_abs];
  const float bo  = bias[2 * H_ + j_abs];
  const float bg  = bias[3 * H_ + j_abs];
  const int mbase = m0 + w * 16 + (l >> 4) * 4;
#pragma unroll
  for (int r = 0; r < 4; ++r) {
    const int m_abs = mbase + r;
    float zi = acc[0][r] + bi;
    float zf = acc[1][r] + bfv;
    float zo = acc[2][r] + bo;
    float zg = acc[3][r] + bg;
    float cn = sigf(zf) * cv[r] + sigf(zi) * tanhf(zg);
    float hn = sigf(zo) * tanhf(cn);
    cv[r] = cn;
    const size_t off = (size_t)m_abs * H_ + j_abs;
    unsigned short hi = f2bf(hn);
    sth_coh(hhi + off, hi);
    sth_coh(hlo + off, f2bf(hn - bf2f(hi)));
    if (STORE_LO0)
      sth_coh((short*)(lo0_t + (size_t)m_abs * NSEQH + j_abs), f2h(hn));
  }
}

// ---------------------------------------------------------------------------
// Persistent kernel: per-band (64-row) flag sync, system-coherent data path.
// ---------------------------------------------------------------------------
__global__ __launch_bounds__(256, 1) void persist(
    const float* inputs,
    const float* W0, const float* b0, const float* Wd0, const float* bd0,
    const float* W1, const float* b1, const float* Wd1, const float* bd1,
    float* out,
    unsigned short* lo0, short* xinhi, short* xinlo,
    short* hhi, short* hlo, short* huhi, short* hulo,
    short* xhhi, short* xhlo,
    float* Tm1T, short* Wd0s, short* Wd1s, short* W0s, short* W1s,
    unsigned* bar, int* xcdmap)
{
  __shared__ __align__(16) char LDS[131072];
  const int gtid = blockIdx.x * 256 + threadIdx.x;

  if (threadIdx.x == 0) {
    unsigned xcc;
    asm volatile("s_getreg_b32 %0, hwreg(20, 0, 32)" : "=s"(xcc)); // HW_REG_XCC_ID
    xcdmap[blockIdx.x] = (int)(xcc & 7u);
  }

  auto dosplit = [&](const float* W, short* Ws, int N, int Ksrc, int Kpad, int pad_at) {
    const int total = N * Kpad;
    for (int idx = gtid; idx < total; idx += NTHR) {
      int n = idx / Kpad, c = idx - n * Kpad;
      int sc = c;
      if (pad_at >= 0) { if (c == pad_at) sc = -1; else if (c > pad_at) sc = c - 1; }
      float v = 0.f;
      if (sc >= 0 && sc < Ksrc) v = W[(size_t)n * Ksrc + sc];
      unsigned short hi = f2bf(v);
      unsigned short lo = f2bf(v - bf2f(hi));
      size_t base = (size_t)n * (2 * Kpad);
      Ws[base + c]        = (short)hi;
      Ws[base + Kpad + c] = (short)lo;
    }
  };
  dosplit(Wd0, Wd0s, 512, 512, 512, -1);
  dosplit(Wd1, Wd1s, 512, 512, 512, -1);
  dosplit(W0, W0s, 2048, 575, 576, 63);
  dosplit(W1, W1s, 2048, 1024, 1024, -1);
  for (int idx = gtid; idx < B_ * SEQ_ * 64; idx += NTHR) {
    float v = inputs[idx];
    unsigned short hi = f2bf(v);
    xinhi[idx] = (short)hi;
    xinlo[idx] = (short)f2bf(v - bf2f(hi));
  }
  for (int idx = gtid; idx < B_ * SEQ_; idx += NTHR) {
    int b = idx / SEQ_, t = idx - b * SEQ_;
    float dt = inputs[(size_t)b * (SEQ_ * 64) + t * 64 + 63];
    Tm1T[t * B_ + b] = 1.0f / logf(dt + 2.7183f) - 1.0f;
  }
  for (int idx = gtid; idx < B_ * H_; idx += NTHR) {
    hhi[idx] = 0; hlo[idx] = 0;
  }
  gbar_heavy(bar);

  const int myw = compute_slot(xcdmap, blockIdx.x);
  const int wg = myw >> 5, rr = myw & 31;
  const int g1_n0 = (wg * 2 + (rr & 1)) * 32;   // 16 n-slices, 2 per XCD
  const int g1_m0 = (rr >> 1) * 32;             // 16 m-tiles per n
  const int g2_j0 = (wg * 4 + (rr & 3)) * 16;   // 32 j-slices, 4 per XCD
  const int g2_m0 = (rr >> 2) * 64;             // 8 m-tiles per j

  const int t = rr >> 2;                 // band 0..7 (rows 64t..64t+63)
  const int cid = wg * 4 + (rr & 3);     // 0..31 within band
  unsigned* g1d = bar + 512 + t * 32;    // per-band monotonic counters
  unsigned* g2d = bar + 768 + t * 32;
  unsigned* zd  = bar + 256 + t * 32;

  for (int layer = 0; layer < 2; ++layer) {
    f32x4 cv = {0.f, 0.f, 0.f, 0.f};
    if (layer == 1) {
      flag_wait(g2d, 32u * SEQ_);
      const size_t base = (size_t)t * 64 * H_;
      for (int i = cid * 256 + threadIdx.x; i < 64 * H_; i += 32 * 256) {
        sth_coh(hhi + base + i, 0); sth_coh(hlo + base + i, 0);
      }
      flag_signal(zd);
      flag_wait(zd, 32u);
    }
    for (int s = 0; s < SEQ_; ++s) {
      const unsigned ss = (unsigned)(layer * SEQ_ + s);
      const int torig = SEQ_ - 1 - s;
      flag_wait(g2d, 32u * ss);            // band h(s-1) ready; hu WAR clear
      if (layer == 0)
        g1_phase<false>(LDS, g1_m0, g1_n0, hhi, hlo, Wd0s, bd0,
                        Tm1T + (size_t)torig * B_, huhi, hulo,
                        nullptr, nullptr, nullptr);
      else
        g1_phase<true>(LDS, g1_m0, g1_n0, hhi, hlo, Wd1s, bd1,
                       Tm1T + (size_t)torig * B_, huhi, hulo,
                       lo0 + (size_t)torig * H_, xhhi, xhlo);
      flag_signal(g1d);
      flag_wait(g1d, 32u * (ss + 1));      // band hu/xh ready
      if (layer == 0)
        g2_phase<576, 64, SEQ_ * 64, true, false>(
            LDS, g2_m0, g2_j0,
            xinhi + (size_t)torig * 64, xinlo + (size_t)torig * 64,
            huhi, hulo, W0s, b0, cv, hhi, hlo,
            lo0 + (size_t)s * H_);
      else
        g2_phase<1024, 512, H_, false, true>(
            LDS, g2_m0, g2_j0,
            xhhi, xhlo, huhi, hulo, W1s, b1,
            cv, hhi, hlo, nullptr);
      flag_signal(g2d);
    }
  }

  // band-local output writeback (wait for whole band's last G2)
  flag_wait(g2d, 32u * (unsigned)(2 * SEQ_));
  {
    const size_t base = (size_t)t * 64 * H_;
    for (int i = cid * 256 + threadIdx.x; i < 64 * H_; i += 32 * 256)
      out[base + i] = bf2f(ldh_coh((const unsigned short*)hhi + base + i)) +
                      bf2f(ldh_coh((const unsigned short*)hlo + base + i));
  }
}

extern "C" void kernel_launch(void* const* d_in, const int* in_sizes, int n_in,
                              void* d_out, int out_size, void* d_ws, size_t ws_size,
                              hipStream_t stream) {
  const float* inputs = (const float*)d_in[0];
  const float* W0  = (const float*)d_in[1];
  const float* b0  = (const float*)d_in[2];
  const float* Wd0 = (const float*)d_in[3];
  const float* bd0 = (const float*)d_in[4];
  const float* W1  = (const float*)d_in[5];
  const float* b1  = (const float*)d_in[6];
  const float* Wd1 = (const float*)d_in[7];
  const float* bd1 = (const float*)d_in[8];

  char* ws = (char*)d_ws;
  size_t off = 0;
  auto alloc = [&](size_t bytes) -> char* {
    char* p = ws + off;
    off += (bytes + 1023) & ~(size_t)1023;
    return p;
  };
  unsigned* bar = (unsigned*)alloc(4096);
  int* xcdmap = (int*)alloc(NBLK * 4);
  unsigned short* lo0 = (unsigned short*)alloc((size_t)B_ * SEQ_ * H_ * 2); // fp16
  short* xinhi = (short*)alloc((size_t)B_ * SEQ_ * 64 * 2);
  short* xinlo = (short*)alloc((size_t)B_ * SEQ_ * 64 * 2);
  short* hhi   = (short*)alloc((size_t)B_ * H_ * 2);
  short* hlo   = (short*)alloc((size_t)B_ * H_ * 2);
  short* huhi  = (short*)alloc((size_t)B_ * H_ * 2);
  short* hulo  = (short*)alloc((size_t)B_ * H_ * 2);
  short* xhhi  = (short*)alloc((size_t)B_ * H_ * 2);
  short* xhlo  = (short*)alloc((size_t)B_ * H_ * 2);
  float* Tm1T  = (float*)alloc((size_t)SEQ_ * B_ * 4);
  short* Wd0s  = (short*)alloc((size_t)512 * 1024 * 2);
  short* Wd1s  = (short*)alloc((size_t)512 * 1024 * 2);
  short* W0s   = (short*)alloc((size_t)2048 * 1152 * 2);
  short* W1s   = (short*)alloc((size_t)2048 * 2048 * 2);

  if (off > ws_size) {
    fill_kernel<<<(out_size + 255) / 256, 256, 0, stream>>>(
        (float*)d_out, out_size, (float)(ws_size >> 20));
    return;
  }

  hipMemsetAsync(bar, 0, 4096, stream);
  persist<<<NBLK, 256, 0, stream>>>(
      inputs, W0, b0, Wd0, bd0, W1, b1, Wd1, bd1,
      (float*)d_out,
      lo0, xinhi, xinlo,
      hhi, hlo, huhi, hulo, xhhi, xhlo,
      Tm1T, Wd0s, Wd1s, W0s, W1s, bar, xcdmap);
}